// Round 10
// baseline (230.570 us; speedup 1.0000x reference)
//
#include <hip/hip_runtime.h>

// SSIM (window=8 box sums) over 96 images of 512x512 fp32.
// v15 = v14 (TH=64, best structure, ~90us) + 4-deep prefetch slot ring.
//  - v14 post-mortem: bytes cut 23%, dur flat -> delivered RATE fell 3.0->
//    2.25 TB/s.  Little's law: BW = inflight/latency.  v8: 12 blk/CU x 8KB;
//    v14: 3 blk/CU x 8KB.  Low-bytes AND high-inflight never tried.
//  - v15: pf slots [4][2 rows]; slot g&3 consumed at group g, refilled for
//    group g+4 -> consumption 4 groups behind issue -> counted vmcnt(12)
//    (v12 lesson: consumed loads must be the OLDEST outstanding).  24 KB
//    in flight per block (3x v14).  Slot period (8 rows) == ring period.
//  - __launch_bounds__(128) (no min): pf +48 VGPR -> ~165 total; the old
//    (128,2) cap of 128 would spill (v7/v9 lesson).  ~165 -> 8 waves/CU
//    >= 6 resident needed; LDS 16.9KB x 3 blocks fine.
// Tripwires: WRITE_SIZE >> 100 KB => spill (then depth 3); VGPR <= ~200.

#define W 512
#define H 512
#define OW 505
#define OH 505
#define TH 64
#define NSTRIP ((OH + TH - 1) / TH)   // 8
#define NIMG 96
#define NPIX (96.0 * 505.0 * 505.0)   // 24482400

__device__ __forceinline__ float4 ld4(const float* p) { return *(const float4*)p; }
__device__ __forceinline__ float4 f4add(float4 a, float4 b) {
    return make_float4(a.x + b.x, a.y + b.y, a.z + b.z, a.w + b.w);
}
__device__ __forceinline__ float4 f4sub(float4 a, float4 b) {
    return make_float4(a.x - b.x, a.y - b.y, a.z - b.z, a.w - b.w);
}
__device__ __forceinline__ float4 f4mul(float4 a, float4 b) {
    return make_float4(a.x * b.x, a.y * b.y, a.z * b.z, a.w * b.w);
}

// LDS-only barrier: order this wave's ds ops, then sync the block.
// NOT __syncthreads(): that drains vmcnt(0), killing prefetch flight.
__device__ __forceinline__ void wbar() {
    asm volatile("s_waitcnt lgkmcnt(0)" ::: "memory");
    __builtin_amdgcn_s_barrier();
}

__global__ void finalize(const double* p, float* out) {
    out[0] = 1.0f - (float)(*p / NPIX);
}

__global__ void __launch_bounds__(128)
ssim_main(const float* __restrict__ gt, const float* __restrict__ ni,
          double* __restrict__ acc_out)
{
    const int t   = threadIdx.x;      // 0..127
    const int c0  = t * 4;            // base column (0..508)
    const int img = blockIdx.y;
    const int R0  = blockIdx.x * TH;  // first output row of strip (mult of 8)
    const int R1  = min(R0 + TH, OH);

    const float C1 = 1e-4f;
    const float C2 = 9e-4f;

    const float* gx = gt + (size_t)img * (W * H) + c0;
    const float* gy = ni + (size_t)img * (W * H) + c0;

    // 2 row-slots x 4 quantities x 520 cols (width 520: threads 126/127 read
    // past col 511 -> garbage, predicated out of the accumulate).
    __shared__ float vbuf[2][4][520];
    __shared__ float wpart[2];

    float4 ring_x[8], ring_y[8];
    float4 vsx = make_float4(0, 0, 0, 0);   // sum x
    float4 vsy = make_float4(0, 0, 0, 0);   // sum y
    float4 vsq = make_float4(0, 0, 0, 0);   // sum x^2 + y^2
    float4 vsp = make_float4(0, 0, 0, 0);   // sum x*y

    // warm-up: rows R0..R0+6 -> ring slots 0..6; slot 7 = zeros
#pragma unroll
    for (int k = 0; k < 7; ++k) {
        float4 x = ld4(gx + (size_t)(R0 + k) * W);
        float4 y = ld4(gy + (size_t)(R0 + k) * W);
        ring_x[k] = x; ring_y[k] = y;
        vsx = f4add(vsx, x);
        vsy = f4add(vsy, y);
        vsq = f4add(vsq, f4add(f4mul(x, x), f4mul(y, y)));
        vsp = f4add(vsp, f4mul(x, y));
    }
    ring_x[7] = make_float4(0, 0, 0, 0);
    ring_y[7] = make_float4(0, 0, 0, 0);

    // prefetch slot ring: slot s primed with rows R0+7+2s, R0+8+2s
    // (max primed row R0+14 <= 462 < 512, always valid).
    float4 pfx[4][2], pfy[4][2];
#define PRIME(s) {                                                        \
        pfx[s][0] = ld4(gx + (size_t)(R0 + 7 + 2 * (s)) * W);             \
        pfy[s][0] = ld4(gy + (size_t)(R0 + 7 + 2 * (s)) * W);             \
        pfx[s][1] = ld4(gx + (size_t)(R0 + 8 + 2 * (s)) * W);             \
        pfy[s][1] = ld4(gy + (size_t)(R0 + 8 + 2 * (s)) * W);             \
    }
    PRIME(0) PRIME(1) PRIME(2) PRIME(3)

    float acc = 0.0f;

// phase A, one row: consume pf slot P row m, slide vsums, publish LDS row m
#define PHASEA_ROW(rb, m, slot, P) {                                      \
        if ((rb) + (m) < R1) { /* block-uniform */                        \
            float4 cx = pfx[P][m], cy = pfy[P][m];                        \
            float4 ox = ring_x[slot], oy = ring_y[slot];                  \
            vsx = f4add(f4sub(vsx, ox), cx);                              \
            vsy = f4add(f4sub(vsy, oy), cy);                              \
            vsq = f4add(vsq, f4sub(f4add(f4mul(cx, cx), f4mul(cy, cy)),   \
                                   f4add(f4mul(ox, ox), f4mul(oy, oy)))); \
            vsp = f4add(vsp, f4sub(f4mul(cx, cy), f4mul(ox, oy)));        \
            ring_x[slot] = cx; ring_y[slot] = cy;                         \
            *(float4*)&vbuf[m][0][c0] = vsx;                              \
            *(float4*)&vbuf[m][1][c0] = vsy;                              \
            *(float4*)&vbuf[m][2][c0] = vsq;                              \
            *(float4*)&vbuf[m][3][c0] = vsp;                              \
        }                                                                 \
    }

// 8-wide horizontal sliding sums from 3 LDS float4s (own, +4, +8)
#define HORIZ(q) {                                                        \
        float4 o = *(float4*)&vbuf[m][q][c0];                             \
        float4 a = *(float4*)&vbuf[m][q][c0 + 4];                         \
        float4 e = *(float4*)&vbuf[m][q][c0 + 8];                         \
        float s = ((o.x + o.y) + (o.z + o.w)) +                           \
                  ((a.x + a.y) + (a.z + a.w));                            \
        B[q][0] = s;                                                      \
        s += e.x - o.x; B[q][1] = s;                                      \
        s += e.y - o.y; B[q][2] = s;                                      \
        s += e.z - o.z; B[q][3] = s;                                      \
    }

// phase B, one row: horizontal sums + SSIM + accumulate
#define PHASEB_ROW(rb, mm) {                                              \
        if ((rb) + (mm) < R1) { /* block-uniform */                       \
            const int m = (mm);                                           \
            float B[4][4];                                                \
            HORIZ(0) HORIZ(1) HORIZ(2) HORIZ(3)                           \
            _Pragma("unroll")                                             \
            for (int j = 0; j < 4; ++j) {                                 \
                float Sx = B[0][j], Sy = B[1][j];                         \
                float Sq = B[2][j], Sp = B[3][j];                         \
                float mu12 = Sx * Sy;                                     \
                float n1v = 2.0f * mu12 + C1;                             \
                float n2v = 2.0f * (Sp - mu12) + C2;                      \
                float sx2 = Sx * Sx, sy2 = Sy * Sy;                       \
                float d1  = sx2 + sy2 + C1;                               \
                float d2  = (Sq - sx2 - sy2) + C2;                        \
                float sv  = (n1v * n2v) * __builtin_amdgcn_rcpf(d1 * d2); \
                if (c0 + j < OW) acc += sv;                               \
            }                                                             \
        }                                                                 \
    }

// one group = 2 rows: phase A (consume slot P), bar, refill slot P for
// group rb+8 (rows rb+15, rb+16; guards match that group's PHASEA exactly:
// row rb+15 consumed iff rb+8 < R1, rb+16 iff rb+9 < R1), phase B, bar.
// Max row read: rb+16 with rb+9 < R1 <= 505 -> rb <= 495 -> row <= 511. OK.
// Consumed slot is the OLDEST outstanding (3 slots = 12 loads younger) ->
// compiler emits counted vmcnt, no drain.
#define GROUP2(rb, s0, s1, P) {                                           \
        if ((rb) < R1) { /* block-uniform */                              \
            PHASEA_ROW(rb, 0, s0, P) PHASEA_ROW(rb, 1, s1, P)             \
            wbar();                                                       \
            if ((rb) + 8 < R1) {                                          \
                pfx[P][0] = ld4(gx + (size_t)((rb) + 15) * W);            \
                pfy[P][0] = ld4(gy + (size_t)((rb) + 15) * W);            \
            }                                                             \
            if ((rb) + 9 < R1) {                                          \
                pfx[P][1] = ld4(gx + (size_t)((rb) + 16) * W);            \
                pfy[P][1] = ld4(gy + (size_t)((rb) + 16) * W);            \
            }                                                             \
            PHASEB_ROW(rb, 0) PHASEB_ROW(rb, 1)                           \
            wbar();                                                       \
        }                                                                 \
    }

    // R0 mult of 8: ring slots cycle (7,0),(1,2),(3,4),(5,6) per 8 rows;
    // pf slots cycle 0,1,2,3 per 8 rows -- both period-8, in lockstep.
    for (int rb0 = R0; rb0 < R1; rb0 += 8) {
        GROUP2(rb0,     7, 0, 0)
        GROUP2(rb0 + 2, 1, 2, 1)
        GROUP2(rb0 + 4, 3, 4, 2)
        GROUP2(rb0 + 6, 5, 6, 3)
    }

    // reduction: wave shuffle -> LDS -> one double atomic per block
#pragma unroll
    for (int off = 32; off > 0; off >>= 1) acc += __shfl_down(acc, off);
    const int wave = t >> 6, lane = t & 63;
    if (lane == 0) wpart[wave] = acc;
    __syncthreads();
    if (t == 0) atomicAdd(acc_out, (double)(wpart[0] + wpart[1]));
}

extern "C" void kernel_launch(void* const* d_in, const int* in_sizes, int n_in,
                              void* d_out, int out_size, void* d_ws, size_t ws_size,
                              hipStream_t stream) {
    const float* gt = (const float*)d_in[0];
    const float* ni = (const float*)d_in[1];
    double* acc = (double*)d_ws;   // 8 bytes scratch, re-poisoned every call

    hipMemsetAsync(acc, 0, sizeof(double), stream);
    dim3 grid(NSTRIP, NIMG);
    ssim_main<<<grid, 128, 0, stream>>>(gt, ni, acc);
    finalize<<<1, 1, 0, stream>>>(acc, (float*)d_out);
}